// Round 1
// baseline (2949.182 us; speedup 1.0000x reference)
//
#include <hip/hip_runtime.h>

#define B_ 2048
#define T_ 48
#define V_ 59
#define H_ 512
#define KP_ 640   // padded K for gates GEMM (59+59+512+10)
#define G4_ 2048  // 4*H

typedef __bf16 bf16x8 __attribute__((ext_vector_type(8)));
typedef float f32x4 __attribute__((ext_vector_type(4)));

__device__ __forceinline__ unsigned short f2bf(float x){
  union { float f; unsigned u; } v; v.f = x;
  unsigned r = (v.u + 0x7FFFu + ((v.u >> 16) & 1u)) >> 16;
  return (unsigned short)r;
}
__device__ __forceinline__ float sigf(float x){ return 1.f/(1.f+expf(-x)); }

// ---- workspace layout (bytes) ----
static const size_t OFF_Hws = 0;                               // h fp32 [2048*512]
static const size_t OFF_Cws = 4194304;                         // c fp32 [2048*512]
static const size_t OFF_LN  = 8388608;                         // loss_num[48] f32
static const size_t OFF_LD  = OFF_LN + 256;                    // loss_den[48] f32
static const size_t MEMSET_BYTES = OFF_LN + 512;               // zero h, c, loss
static const size_t OFF_A   = OFF_LN + 512;                    // A bf16 [2048*640]
static const size_t OFF_WGT = OFF_A  + (size_t)B_*KP_*2;       // WgT bf16 [2048*640]
static const size_t OFF_WGH = OFF_WGT + (size_t)G4_*KP_*2;     // WghT f32 [59*512]
static const size_t OFF_WHI = OFF_WGH + (size_t)V_*H_*4;       // WhistT f32 [512*59]
static const size_t OFF_WFR = OFF_WHI + (size_t)H_*V_*4;       // WfrT f32 [59*59]
static const size_t OFF_WWC = OFF_WFR + 14080;                 // WwcT f32 [118*59]

// ------------------- init: build transposed / packed weights -------------------
__global__ void init_k(const float* __restrict__ W_gh, const float* __restrict__ W_hist,
                       const float* __restrict__ W_fr, const float* __restrict__ W_wc,
                       const float* __restrict__ W_ih, const float* __restrict__ W_hh,
                       float* __restrict__ WghT, float* __restrict__ WhistT,
                       float* __restrict__ WfrT, float* __restrict__ WwcT,
                       unsigned short* __restrict__ WgT)
{
  int tid = blockIdx.x*blockDim.x + threadIdx.x;
  int nt  = gridDim.x*blockDim.x;
  // WghT[v*512+j] = W_gh[j*59+v]
  for (int i = tid; i < V_*H_; i += nt){ int v = i >> 9, j = i & 511; WghT[i] = W_gh[j*V_ + v]; }
  // WhistT[j*59+v] = W_hist[v*512+j]
  for (int i = tid; i < H_*V_; i += nt){ int j = i / V_, v = i - j*V_; WhistT[i] = W_hist[v*H_ + j]; }
  // WfrT[u*59+v] = (u==v) ? 0 : W_fr[v*59+u]
  for (int i = tid; i < V_*V_; i += nt){ int u = i / V_, v = i - u*V_; WfrT[i] = (u==v) ? 0.f : W_fr[v*V_ + u]; }
  // WwcT[u*59+v] = W_wc[v*118+u]
  for (int i = tid; i < 2*V_*V_; i += nt){ int u = i / V_, v = i - u*V_; WwcT[i] = W_wc[v*(2*V_) + u]; }
  // WgT[n*640+k]: k<118 -> W_ih[n][k]; k<630 -> W_hh[n][k-118]; else 0
  for (int i = tid; i < G4_*KP_; i += nt){
    int n = i / KP_, k = i - n*KP_;
    float v = 0.f;
    if (k < 2*V_)      v = W_ih[n*(2*V_) + k];
    else if (k < 630)  v = W_hh[n*H_ + (k-118)];
    WgT[i] = f2bf(v);
  }
}

// ------------------- phase 1: decay, history, regression, combine -------------------
__global__ __launch_bounds__(512) void phase1(int t,
    const float* __restrict__ x, const float* __restrict__ mk, const float* __restrict__ dl,
    const float* __restrict__ b_gh, const float* __restrict__ w_gx, const float* __restrict__ b_gx,
    const float* __restrict__ b_hist, const float* __restrict__ b_fr, const float* __restrict__ b_wc,
    const float* __restrict__ WghT, const float* __restrict__ WhistT,
    const float* __restrict__ WfrT, const float* __restrict__ WwcT,
    const float* __restrict__ h_ws, unsigned short* __restrict__ A_buf,
    float* __restrict__ out_ximp, float* __restrict__ loss_num, float* __restrict__ loss_den)
{
  __shared__ float d_s[8*64], m_s[8*64], x_s[8*64];
  __shared__ float hs[8*H_];                 // decayed hidden (fp32)
  __shared__ float xh_s[8*64], xr_s[8*64], gx_s[8*64];
  __shared__ float red[16];
  const int tid = threadIdx.x;
  const int r0  = blockIdx.x * 8;

  if (tid < 8*V_) {
    int b = tid / V_, v = tid - b*V_;
    size_t g = ((size_t)(r0+b)*T_ + t)*V_ + v;
    d_s[b*64+v] = dl[g];
    m_s[b*64+v] = mk[g];
    x_s[b*64+v] = x[g];
  }
  __syncthreads();

  // gamma_h and h~ ; thread = hidden unit j (512 threads)
  {
    int j = tid;
    float acc[8];
#pragma unroll
    for (int b=0;b<8;++b) acc[b]=0.f;
    for (int v=0; v<V_; ++v) {
      float wv = WghT[v*H_ + j];
#pragma unroll
      for (int b=0;b<8;++b) acc[b] += d_s[b*64+v]*wv;
    }
    float bg = b_gh[j];
#pragma unroll
    for (int b=0;b<8;++b) {
      float gh = expf(-fmaxf(acc[b]+bg, 0.f));
      float hv = h_ws[(size_t)(r0+b)*H_ + j] * gh;
      hs[b*H_+j] = hv;
      A_buf[(size_t)(r0+b)*KP_ + 118 + j] = f2bf(hv);
    }
  }
  // zero K-pad columns of A
  if (tid < 128) { int b = tid>>4, p = tid&15; if (p < 10) A_buf[(size_t)(r0+b)*KP_ + 630 + p] = 0; }
  __syncthreads();

  // x_h = h~ @ W_hist^T + b_hist ; then x_r, gamma_x
  {
    int b = tid>>6, v = tid&63;
    if (v < V_) {
      const float* hp = &hs[b*H_];
      float a0=0.f,a1=0.f,a2=0.f,a3=0.f;
      for (int j=0;j<H_;j+=4){
        a0 += hp[j  ]*WhistT[(j  )*V_+v];
        a1 += hp[j+1]*WhistT[(j+1)*V_+v];
        a2 += hp[j+2]*WhistT[(j+2)*V_+v];
        a3 += hp[j+3]*WhistT[(j+3)*V_+v];
      }
      float xh = b_hist[v] + ((a0+a1)+(a2+a3));
      float mm = m_s[b*64+v], xx = x_s[b*64+v], dd = d_s[b*64+v];
      xh_s[b*64+v] = xh;
      xr_s[b*64+v] = mm*xx + (1.f-mm)*xh;
      gx_s[b*64+v] = expf(-fmaxf(dd*w_gx[v]+b_gx[v], 0.f));
      A_buf[(size_t)(r0+b)*KP_ + V_ + v] = f2bf(mm);
    }
  }
  __syncthreads();

  // xu (feature regression), beta, x_comb, x_imp, loss partials
  float num = 0.f, den = 0.f;
  {
    int b = tid>>6, v = tid&63;
    if (v < V_) {
      float xu = b_fr[v], bt = b_wc[v];
      for (int u=0; u<V_; ++u) {
        xu += xr_s[b*64+u]*WfrT[u*V_+v];
        bt += gx_s[b*64+u]*WwcT[u*V_+v] + m_s[b*64+u]*WwcT[(V_+u)*V_+v];
      }
      float xh = xh_s[b*64+v];
      float xc = bt*xu + (1.f-bt)*xh;
      float mm = m_s[b*64+v], xx = x_s[b*64+v];
      num = fabsf(xx - xc)*mm;
      den = mm;
      float xi = mm*xx + (1.f-mm)*xc;
      out_ximp[((size_t)(r0+b)*T_ + t)*V_ + v] = xi;
      A_buf[(size_t)(r0+b)*KP_ + v] = f2bf(xi);
    }
  }
  // block reduction for loss
#pragma unroll
  for (int off=32; off; off>>=1){ num += __shfl_down(num, off); den += __shfl_down(den, off); }
  int wid = tid>>6, lane = tid&63;
  if (lane == 0){ red[wid] = num; red[8+wid] = den; }
  __syncthreads();
  if (tid == 0){
    float n=0.f, d=0.f;
    for (int i=0;i<8;++i){ n += red[i]; d += red[8+i]; }
    atomicAdd(&loss_num[t], n);
    atomicAdd(&loss_den[t], d);
  }
}

// ------------------- phase 2: gate GEMM (bf16 MFMA) + LSTM update -------------------
__global__ __launch_bounds__(256) void phase2(int t,
    const unsigned short* __restrict__ A_buf, const unsigned short* __restrict__ WgT,
    const float* __restrict__ b_ih, const float* __restrict__ b_hh,
    float* __restrict__ h_ws, float* __restrict__ c_ws, float* __restrict__ out_hid)
{
  __shared__ unsigned short ldsA[128*72];   // rows: batch tile, padded stride 72
  __shared__ unsigned short ldsB[128*72];   // rows: gate-col tile [4 gates x 32 units]
  const int tid  = threadIdx.x;
  const int r0   = blockIdx.x * 128;   // batch rows
  const int j0   = blockIdx.y * 32;    // hidden units
  const int w    = tid >> 6;
  const int lane = tid & 63;
  const int col  = lane & 15;
  const int quad = lane >> 4;

  f32x4 acc[2][8];
#pragma unroll
  for (int i=0;i<2;++i)
#pragma unroll
    for (int j=0;j<8;++j) acc[i][j] = (f32x4)(0.f);

  for (int s = 0; s < 10; ++s) {          // K = 640 in 10 stages of 64
#pragma unroll
    for (int p=0; p<4; ++p) {
      int cid = p*256 + tid;
      int row = cid >> 3, c8 = cid & 7;
      uint4 va = *reinterpret_cast<const uint4*>(A_buf + (size_t)(r0+row)*KP_ + s*64 + c8*8);
      *reinterpret_cast<uint4*>(&ldsA[row*72 + c8*8]) = va;
      int ng = ((row>>5)<<9) + j0 + (row&31);   // gate*512 + unit
      uint4 vb = *reinterpret_cast<const uint4*>(WgT + (size_t)ng*KP_ + s*64 + c8*8);
      *reinterpret_cast<uint4*>(&ldsB[row*72 + c8*8]) = vb;
    }
    __syncthreads();
#pragma unroll
    for (int kk=0; kk<2; ++kk) {
      bf16x8 af[2], bfr[8];
#pragma unroll
      for (int mf=0; mf<2; ++mf)
        af[mf] = *reinterpret_cast<const bf16x8*>(&ldsA[(w*32 + mf*16 + col)*72 + kk*32 + quad*8]);
#pragma unroll
      for (int nf=0; nf<8; ++nf)
        bfr[nf] = *reinterpret_cast<const bf16x8*>(&ldsB[(nf*16 + col)*72 + kk*32 + quad*8]);
#pragma unroll
      for (int mf=0; mf<2; ++mf)
#pragma unroll
        for (int nf=0; nf<8; ++nf)
          acc[mf][nf] = __builtin_amdgcn_mfma_f32_16x16x32_bf16(af[mf], bfr[nf], acc[mf][nf], 0, 0, 0);
    }
    __syncthreads();
  }

  // epilogue: nf = 2*gate + uh ; C/D layout: n = lane&15, m = quad*4 + r
#pragma unroll
  for (int uh=0; uh<2; ++uh) {
    int u = j0 + uh*16 + col;
    float bi = b_ih[u]        + b_hh[u];
    float bf_ = b_ih[H_+u]    + b_hh[H_+u];
    float bg = b_ih[2*H_+u]   + b_hh[2*H_+u];
    float bo = b_ih[3*H_+u]   + b_hh[3*H_+u];
#pragma unroll
    for (int mf=0; mf<2; ++mf) {
#pragma unroll
      for (int r=0; r<4; ++r) {
        int b = r0 + w*32 + mf*16 + quad*4 + r;
        float gi = acc[mf][0+uh][r] + bi;
        float gf = acc[mf][2+uh][r] + bf_;
        float gg = acc[mf][4+uh][r] + bg;
        float go = acc[mf][6+uh][r] + bo;
        size_t idx = (size_t)b*H_ + u;
        float co = c_ws[idx];
        float cn = sigf(gf)*co + sigf(gi)*tanhf(gg);
        float hn = sigf(go)*tanhf(cn);
        c_ws[idx] = cn;
        h_ws[idx] = hn;
        out_hid[((size_t)b*T_ + t)*H_ + u] = hn;
      }
    }
  }
}

// ------------------- final loss reduction -------------------
__global__ void loss_k(const float* __restrict__ loss_num, const float* __restrict__ loss_den,
                       float* __restrict__ out_loss)
{
  int tid = threadIdx.x;
  float v = 0.f;
  if (tid < T_) v = loss_num[tid]/(loss_den[tid] + 1e-5f);
#pragma unroll
  for (int off=32; off; off>>=1) v += __shfl_down(v, off);
  if (tid == 0) *out_loss = v;
}

extern "C" void kernel_launch(void* const* d_in, const int* in_sizes, int n_in,
                              void* d_out, int out_size, void* d_ws, size_t ws_size,
                              hipStream_t stream)
{
  const float* x      = (const float*)d_in[0];
  const float* mk     = (const float*)d_in[1];
  const float* dl     = (const float*)d_in[2];
  const float* W_gh   = (const float*)d_in[3];
  const float* b_gh   = (const float*)d_in[4];
  const float* w_gx   = (const float*)d_in[5];
  const float* b_gx   = (const float*)d_in[6];
  const float* W_hist = (const float*)d_in[7];
  const float* b_hist = (const float*)d_in[8];
  const float* W_fr   = (const float*)d_in[9];
  const float* b_fr   = (const float*)d_in[10];
  const float* W_wc   = (const float*)d_in[11];
  const float* b_wc   = (const float*)d_in[12];
  const float* W_ih   = (const float*)d_in[13];
  const float* W_hh   = (const float*)d_in[14];
  const float* b_ih   = (const float*)d_in[15];
  const float* b_hh   = (const float*)d_in[16];

  char* ws = (char*)d_ws;
  float*          h_ws   = (float*)(ws + OFF_Hws);
  float*          c_ws   = (float*)(ws + OFF_Cws);
  float*          lnum   = (float*)(ws + OFF_LN);
  float*          lden   = (float*)(ws + OFF_LD);
  unsigned short* A_buf  = (unsigned short*)(ws + OFF_A);
  unsigned short* WgT    = (unsigned short*)(ws + OFF_WGT);
  float*          WghT   = (float*)(ws + OFF_WGH);
  float*          WhistT = (float*)(ws + OFF_WHI);
  float*          WfrT   = (float*)(ws + OFF_WFR);
  float*          WwcT   = (float*)(ws + OFF_WWC);

  float* out      = (float*)d_out;
  float* out_ximp = out;                                   // [B,T,V]
  float* out_loss = out + (size_t)B_*T_*V_;                // scalar
  float* out_hid  = out + (size_t)B_*T_*V_ + 1;            // [B,T,H]

  hipMemsetAsync(d_ws, 0, MEMSET_BYTES, stream);
  init_k<<<1024, 256, 0, stream>>>(W_gh, W_hist, W_fr, W_wc, W_ih, W_hh,
                                   WghT, WhistT, WfrT, WwcT, WgT);
  for (int t = 0; t < T_; ++t) {
    phase1<<<256, 512, 0, stream>>>(t, x, mk, dl, b_gh, w_gx, b_gx, b_hist, b_fr, b_wc,
                                    WghT, WhistT, WfrT, WwcT, h_ws, A_buf,
                                    out_ximp, lnum, lden);
    phase2<<<dim3(16,16), 256, 0, stream>>>(t, A_buf, WgT, b_ih, b_hh,
                                            h_ws, c_ws, out_hid);
  }
  loss_k<<<1, 64, 0, stream>>>(lnum, lden, out_loss);
}